// Round 20
// baseline (237.734 us; speedup 1.0000x reference)
//
#include <hip/hip_runtime.h>

#define BATCH 16
#define TXT   320
#define NMELC 80
#define MELT  2000
#define PADM  1.0e12f
#define L2E   1.4426950408889634f
#define LN2   0.6931471805599453f
#define EPSL2 1.4426950e-7f

typedef __attribute__((ext_vector_type(8))) short bf16x8;
typedef __attribute__((ext_vector_type(4))) float f32x4;

__device__ __forceinline__ short f2bf(float x) {
    unsigned u = __float_as_uint(x);
    unsigned r = (u + 0x7FFFu + ((u >> 16) & 1u)) >> 16;
    return (short)r;
}
__device__ __forceinline__ float dpp_shr1(float x) {
    return __int_as_float(__builtin_amdgcn_update_dpp(
        0, __float_as_int(x), 0x138 /*wave_shr:1*/, 0xF, 0xF, false));
}

// ---------------------------------------------------------------------------
// Kernel A (MFMA, conflict-free staging — verified r19, lp ~30us).
// ---------------------------------------------------------------------------
__global__ __launch_bounds__(256) void lp_kernel(
    const float* __restrict__ mlv,   // (B,320,160)
    const float* __restrict__ ms,    // (B,80,2000)
    float* __restrict__ out_lp)      // (B,320,2000)  (d_out+1)
{
    __shared__ short Ash[20][64][8];    // 20.5 KB
    __shared__ short Bsh[20][128][8];   // 41 KB
    __shared__ float bias_p[256];
    __shared__ float bias_s[64];

    const int b   = blockIdx.z;
    const int j0  = blockIdx.y * 64;
    const int t0  = blockIdx.x * 128;
    const int tid = threadIdx.x;
    const int wv  = tid >> 6;
    const int l   = tid & 63;
    const float s = -0.00625f;

    const float* mlv_b = mlv + (size_t)b * TXT * 160;
    const float* ms_b  = ms  + (size_t)b * NMELC * MELT;

    {
        const int jj = tid >> 2;
        const int q  = tid & 3;
        const float* p = mlv_b + (size_t)(j0 + jj) * 160 + q * 20;
        float part = 0.f;
        #pragma unroll
        for (int c = 0; c < 20; ++c) {
            float mu = p[c];
            float lv = p[c + 80];
            float iv = __expf(-lv);
            part += mu * mu * iv + lv;
        }
        bias_p[tid] = part;
    }
    __syncthreads();
    if (tid < 64) {
        float v = bias_p[tid * 4] + bias_p[tid * 4 + 1] +
                  bias_p[tid * 4 + 2] + bias_p[tid * 4 + 3];
        bias_s[tid] = s * v;
    }

    #pragma unroll
    for (int r = 0; r < 5; ++r) {
        int idx = r * 256 + tid;
        int kb  = idx >> 6;
        int j   = idx & 63;
        const float* rowm = mlv_b + (size_t)(j0 + j) * 160;
        short v[8];
        if (kb < 10) {
            int c0 = kb * 8;
            #pragma unroll
            for (int e = 0; e < 8; ++e) {
                float lv = rowm[80 + c0 + e];
                v[e] = f2bf(s * __expf(-lv));
            }
        } else {
            int c0 = (kb - 10) * 8;
            #pragma unroll
            for (int e = 0; e < 8; ++e) {
                float mu = rowm[c0 + e];
                float lv = rowm[80 + c0 + e];
                v[e] = f2bf(-2.f * s * mu * __expf(-lv));
            }
        }
        *(bf16x8*)&Ash[kb][j][0] = *(bf16x8*)v;
    }

    #pragma unroll
    for (int r = 0; r < 5; ++r) {
        int unit  = r * 4 + wv;
        int kbase = unit >> 1;
        int tg    = unit & 1;
        int t     = t0 + tg * 64 + l;
        int c0    = kbase * 8;
        short vx2[8], vx[8];
        #pragma unroll
        for (int e = 0; e < 8; ++e) {
            float x = (t < MELT) ? ms_b[(size_t)(c0 + e) * MELT + t] : 0.f;
            vx2[e] = f2bf(x * x);
            vx[e]  = f2bf(x);
        }
        *(bf16x8*)&Bsh[kbase][tg * 64 + l][0]      = *(bf16x8*)vx2;
        *(bf16x8*)&Bsh[10 + kbase][tg * 64 + l][0] = *(bf16x8*)vx;
    }
    __syncthreads();

    const int lr = l & 15;
    const int lg = l >> 4;

    f32x4 acc[8];
    #pragma unroll
    for (int f = 0; f < 8; ++f) acc[f] = (f32x4){0.f, 0.f, 0.f, 0.f};

    #pragma unroll
    for (int ks = 0; ks < 5; ++ks) {
        const int kb = ks * 4 + lg;
        bf16x8 a = *(const bf16x8*)&Ash[kb][wv * 16 + lr][0];
        #pragma unroll
        for (int f = 0; f < 8; ++f) {
            bf16x8 bb = *(const bf16x8*)&Bsh[kb][f * 16 + lr][0];
            acc[f] = __builtin_amdgcn_mfma_f32_16x16x32_bf16(a, bb, acc[f],
                                                             0, 0, 0);
        }
    }

    float bs[4];
    #pragma unroll
    for (int r = 0; r < 4; ++r) bs[r] = bias_s[wv * 16 + lg * 4 + r];
    #pragma unroll
    for (int f = 0; f < 8; ++f) {
        int t = t0 + f * 16 + lr;
        if (t < MELT) {
            #pragma unroll
            for (int r = 0; r < 4; ++r) {
                int j = j0 + wv * 16 + lg * 4 + r;
                out_lp[((size_t)b * TXT + j) * MELT + t] = acc[f][r] + bs[r];
            }
        }
    }
}

// ---------------------------------------------------------------------------
// Kernel B: forward DP — r9/r17 loop VERBATIM, lse interior replaced by a
// full-rate polynomial softplus (no v_exp/v_log on the serial chain):
//   x = min(|d|,28); n = floor(x); f = x-n;
//   e = 2^-x  via deg-4 poly(f) * as_float((127-n)<<23)   [err <= 1.2e-3]
//   log2(1+e) = e + e(1-e)*(0.4426950 - 0.2473350e + 0.0832900e^2)
//                                                          [err <= 5e-4]
// Exact at e=0 and e=1 (absorb / equal-input paths). Loss error ~2e-4.
// ---------------------------------------------------------------------------
__global__ __launch_bounds__(192, 1) void dp_kernel(
    const float* __restrict__ lp,    // (B,320,2000) = out_lp
    const int* __restrict__ tlen,
    const int* __restrict__ mlen,
    float* __restrict__ res,
    float* __restrict__ out0)
{
    __shared__ float bnd[2][2056];
    __shared__ int   prog[2];

    const int b    = blockIdx.x;
    const int tid  = threadIdx.x;
    const int w    = tid >> 6;
    const int l    = tid & 63;
    const int tend = mlen[b] - 1;
    const int tl   = tlen[b];

    if (tid < 2) prog[tid] = 0;

    int j0c = 2 * tid; if (j0c > 318) j0c = 318;   // clamp unused lanes
    const float* r0 = lp + (size_t)(b * TXT + j0c) * MELT;
    const float* r1 = r0 + MELT;

    float A1 = (tid == 0) ? lp[(size_t)b * TXT * MELT] * L2E : -PADM;
    float A2 = -PADM;
    float A1F = A1, A2F = A2;

    if (l == 63 && w < 2) bnd[w][0] = -PADM;
    __syncthreads();

    if (w == 2 && tl < 257) return;   // wave 2 unused

    float ptA2 = -PADM, ptB2 = -PADM;
    const bool is0     = (l == 0);
    const bool isPub   = (l == 63) && (w < 2);
    const bool hasRing = (w > 0);
    int seen = 0;

    const int imax = tend + 63;

    float PA[16], PB[16], PC[16];
    #pragma unroll
    for (int q = 0; q < 8; ++q) { PA[2*q] = r0[1 + q - l]; PA[2*q+1] = r1[1 + q - l]; }
    #pragma unroll
    for (int q = 0; q < 8; ++q) { PB[2*q] = r0[9 + q - l]; PB[2*q+1] = r1[9 + q - l]; }
    #pragma unroll
    for (int q = 0; q < 16; ++q) PA[q] = fmaf(PA[q], L2E, EPSL2);

    const float* p0 = r0 + 17 - l;
    const float* p1 = r1 + 17 - l;

#define RING_RD(BQ_, T0_)                                                    \
    {                                                                        \
        float4 q0_ = *(const float4*)&bnd[w - 1][T0_];                       \
        float4 q1_ = *(const float4*)&bnd[w - 1][(T0_) + 4];                 \
        BQ_[0]=q0_.x; BQ_[1]=q0_.y; BQ_[2]=q0_.z; BQ_[3]=q0_.w;              \
        BQ_[4]=q1_.x; BQ_[5]=q1_.y; BQ_[6]=q1_.z; BQ_[7]=q1_.w;              \
    }
#define RING_POLL(NEED_)                                                     \
    if (seen < (NEED_)) {                                                    \
        int tgt_ = (NEED_) + 32;                                             \
        if (tgt_ > tend - 1) tgt_ = tend - 1;                                \
        if (tgt_ < (NEED_)) tgt_ = (NEED_);                                  \
        volatile int* pv_ = &prog[w - 1];                                    \
        int v_ = *pv_;                                                       \
        while (v_ < tgt_) { __builtin_amdgcn_s_sleep(1); v_ = *pv_; }        \
        seen = v_;                                                           \
        __asm__ volatile("" ::: "memory");                                   \
    }

    float bqC[8];
    if (hasRing) {
        RING_POLL(7)
        RING_RD(bqC, 0)
    } else {
        #pragma unroll
        for (int q = 0; q < 8; ++q) bqC[q] = -PADM;
    }

// polynomial lse (log2 domain): OUT = max(a,b) + log2(1 + 2^-|a-b|)
#define LSE_POLY(A_, PT_, OUT_)                                              \
    {                                                                        \
        float m_ = fmaxf(A_, PT_);                                           \
        float d_ = A_ - PT_;                                                 \
        float x_ = fminf(fabsf(d_), 28.0f);                                  \
        float n_ = floorf(x_);                                               \
        float f_ = x_ - n_;                                                  \
        float q_ = fmaf(f_, 0.0096181f, -0.0555041f);                        \
        q_ = fmaf(f_, q_, 0.2402265f);                                       \
        q_ = fmaf(f_, q_, -0.6931472f);                                      \
        q_ = fmaf(f_, q_, 1.0f);                                             \
        float sc_ = __int_as_float((127 - (int)n_) << 23);                   \
        float e_ = q_ * sc_;                                                 \
        float h_ = fmaf(e_, 0.0832900f, -0.2473350f);                        \
        h_ = fmaf(e_, h_, 0.4426950f);                                       \
        float t_ = fmaf(-e_, e_, e_);                                        \
        OUT_ = m_ + fmaf(t_, h_, e_);                                        \
    }

#define STEP2(Pc_, q_, AQ_)                                                  \
    {                                                                        \
        float pt_ = is0 ? bqC[q_] : ptA2;                                    \
        float l1_, l2_;                                                      \
        LSE_POLY(A1, pt_, l1_)                                               \
        LSE_POLY(A2, A1, l2_)                                                \
        float n1_ = l1_ + Pc_[2 * q_];                                       \
        float n2_ = l2_ + Pc_[2 * q_ + 1];                                   \
        float ns_ = dpp_shr1(n2_);                                           \
        ptA2 = ptB2; ptB2 = ns_;                                             \
        A1 = n1_; A2 = n2_; AQ_ = n2_;                                       \
    }

#define GROUP2_S(Pc_, Pm_, Pl_, I0_)                                         \
{                                                                            \
    float bqN[8];                                                            \
    if (hasRing) {                                                           \
        const int nt0_ = (I0_) + 7;                                          \
        RING_POLL(nt0_ + 7)                                                  \
        RING_RD(bqN, nt0_)                                                   \
    } else {                                                                 \
        _Pragma("unroll") for (int q_=0;q_<8;++q_) bqN[q_] = -PADM;          \
    }                                                                        \
    _Pragma("unroll") for (int q_=0;q_<8;++q_) {                             \
        Pl_[2*q_] = p0[q_]; Pl_[2*q_+1] = p1[q_];                            \
    }                                                                        \
    float aq2[8];                                                            \
    _Pragma("unroll")                                                        \
    for (int q_=0;q_<8;++q_) STEP2(Pc_, q_, aq2[q_])                         \
    if (isPub) {                                                             \
        const int t63_ = (I0_) - 63;                                         \
        if (t63_ >= 1) {                                                     \
            _Pragma("unroll") for (int q_=0;q_<8;++q_)                       \
                bnd[w][t63_ + q_] = aq2[q_];                                 \
        } else {                                                             \
            _Pragma("unroll") for (int q_=0;q_<8;++q_)                       \
                if (t63_ + q_ >= 1) bnd[w][t63_ + q_] = aq2[q_];             \
        }                                                                    \
        __asm__ volatile("" ::: "memory");  /* DS pipe is in-order */        \
        int pgv_ = t63_ + 7;                                                 \
        if (pgv_ >= 1) prog[w] = pgv_;                                       \
    }                                                                        \
    p0 += 8; p1 += 8;                                                        \
    _Pragma("unroll") for (int q_=0;q_<16;++q_)                              \
        Pm_[q_] = fmaf(Pm_[q_], L2E, EPSL2);                                 \
    _Pragma("unroll") for (int q_=0;q_<8;++q_) bqC[q_] = bqN[q_];            \
}

#define GROUP2_T(Pc_, Pm_, Pl_, I0_)                                         \
{                                                                            \
    float bqN[8];                                                            \
    if (hasRing) {                                                           \
        const int nt0_ = (I0_) + 7;                                          \
        int need_ = nt0_ + 7; if (need_ > tend - 1) need_ = tend - 1;        \
        RING_POLL(need_)                                                     \
        const int rb_ = nt0_ > 2048 ? 2048 : nt0_;                           \
        RING_RD(bqN, rb_)                                                    \
    } else {                                                                 \
        _Pragma("unroll") for (int q_=0;q_<8;++q_) bqN[q_] = -PADM;          \
    }                                                                        \
    _Pragma("unroll") for (int q_=0;q_<8;++q_) {                             \
        int t_ = (I0_) + 16 + q_ - l;                                        \
        t_ = t_ < 0 ? 0 : (t_ > tend ? tend : t_);                           \
        Pl_[2*q_] = r0[t_]; Pl_[2*q_+1] = r1[t_];                            \
    }                                                                        \
    float aq2[8];                                                            \
    const int vt_ = (I0_) - l;                                               \
    _Pragma("unroll")                                                        \
    for (int q_=0;q_<8;++q_) {                                               \
        STEP2(Pc_, q_, aq2[q_])                                              \
        bool c_ = (vt_ + q_ == tend);                                        \
        A1F = c_ ? A1 : A1F;                                                 \
        A2F = c_ ? A2 : A2F;                                                 \
    }                                                                        \
    if (isPub) {                                                             \
        const int t63_ = (I0_) - 63;                                         \
        _Pragma("unroll") for (int q_=0;q_<8;++q_) {                         \
            int tq_ = t63_ + q_;                                             \
            if (tq_ >= 1 && tq_ <= tend) bnd[w][tq_] = aq2[q_];              \
        }                                                                    \
        __asm__ volatile("" ::: "memory");                                   \
        int pgv_ = t63_ + 7; if (pgv_ > tend) pgv_ = tend;                   \
        if (pgv_ >= 1) prog[w] = pgv_;                                       \
    }                                                                        \
    _Pragma("unroll") for (int q_=0;q_<16;++q_)                              \
        Pm_[q_] = fmaf(Pm_[q_], L2E, EPSL2);                                 \
    _Pragma("unroll") for (int q_=0;q_<8;++q_) bqC[q_] = bqN[q_];            \
}

    int i0 = 1;
    const int sEnd = tend - 23;   // steady: loads in-bounds, latch can't fire
    int ph = 0;
    while (i0 <= sEnd) {
        GROUP2_S(PA, PB, PC, i0); i0 += 8;
        if (i0 > sEnd) { ph = 1; break; }
        GROUP2_S(PB, PC, PA, i0); i0 += 8;
        if (i0 > sEnd) { ph = 2; break; }
        GROUP2_S(PC, PA, PB, i0); i0 += 8;
    }
    if (ph == 1) {
        #pragma unroll
        for (int q = 0; q < 16; ++q) {
            float tmp = PA[q]; PA[q] = PB[q]; PB[q] = PC[q]; PC[q] = tmp;
        }
    } else if (ph == 2) {
        #pragma unroll
        for (int q = 0; q < 16; ++q) {
            float tmp = PA[q]; PA[q] = PC[q]; PC[q] = PB[q]; PB[q] = tmp;
        }
    }
    while (i0 <= imax) {
        GROUP2_T(PA, PB, PC, i0); i0 += 8;
        if (i0 > imax) break;
        GROUP2_T(PB, PC, PA, i0); i0 += 8;
        if (i0 > imax) break;
        GROUP2_T(PC, PA, PB, i0); i0 += 8;
    }

#undef GROUP2_S
#undef GROUP2_T
#undef STEP2
#undef LSE_POLY
#undef RING_RD
#undef RING_POLL

    if (tid == ((tl - 1) >> 1)) {
        float Af = ((tl - 1) & 1) ? A2F : A1F;
        float v = Af * LN2 / (float)(tend + 1);
        if (res) res[b] = v;
        else     atomicAdd(out0, -v / (float)BATCH);
    }
}

__global__ void zero1_kernel(float* out0) { out0[0] = 0.f; }

__global__ void fin_kernel(const float* __restrict__ res, float* __restrict__ out0)
{
    int l = threadIdx.x;
    float v = (l < BATCH) ? res[l] : 0.f;
    #pragma unroll
    for (int off = 32; off; off >>= 1) v += __shfl_down(v, off);
    if (l == 0) out0[0] = -(v / (float)BATCH);
}

// ---------------------------------------------------------------------------
extern "C" void kernel_launch(void* const* d_in, const int* in_sizes, int n_in,
                              void* d_out, int out_size, void* d_ws, size_t ws_size,
                              hipStream_t stream)
{
    const float* mlv = (const float*)d_in[0];
    const float* ms  = (const float*)d_in[1];
    const int*   tl  = (const int*)d_in[2];
    const int*   ml  = (const int*)d_in[3];
    float* out    = (float*)d_out;
    float* out_lp = out + 1;

    bool res_ok = ws_size >= 64;
    float* res = res_ok ? (float*)d_ws : nullptr;

    dim3 gA(16, 5, 16);   // t-tiles(128), j-tiles(64), batch
    lp_kernel<<<gA, 256, 0, stream>>>(mlv, ms, out_lp);

    if (!res_ok) zero1_kernel<<<1, 1, 0, stream>>>(out);
    dp_kernel<<<BATCH, 192, 0, stream>>>(out_lp, tl, ml, res, out);
    if (res_ok) fin_kernel<<<1, 64, 0, stream>>>(res, out);
}

// Round 21
// 197.318 us; speedup vs baseline: 1.2048x; 1.2048x over previous
//
#include <hip/hip_runtime.h>

#define BATCH 16
#define TXT   320
#define NMELC 80
#define MELT  2000
#define PADM  1.0e12f
#define L2E   1.4426950408889634f
#define LN2   0.6931471805599453f
#define EPSL2 1.4426950e-7f

typedef __attribute__((ext_vector_type(8))) short bf16x8;
typedef __attribute__((ext_vector_type(4))) float f32x4;

__device__ __forceinline__ short f2bf(float x) {
    unsigned u = __float_as_uint(x);
    unsigned r = (u + 0x7FFFu + ((u >> 16) & 1u)) >> 16;
    return (short)r;
}
__device__ __forceinline__ float dpp_shr1(float x) {
    return __int_as_float(__builtin_amdgcn_update_dpp(
        0, __float_as_int(x), 0x138 /*wave_shr:1*/, 0xF, 0xF, false));
}

// ---------------------------------------------------------------------------
// Kernel A (MFMA, conflict-free b128 staging — verified r19, ~30us).
// lp[b,j,t] = sum_k G*F + bias;  k<80: G=s*ivar,F=x^2; k>=80: G=-2s*mu*ivar,F=x.
// Block 64j x 128t, 256 thr; mfma_f32_16x16x32_bf16, 5 K-steps x 8 t-frags.
// C/D: col = lane&15, row = (lane>>4)*4 + reg (HW-verified).
// ---------------------------------------------------------------------------
__global__ __launch_bounds__(256) void lp_kernel(
    const float* __restrict__ mlv,   // (B,320,160)
    const float* __restrict__ ms,    // (B,80,2000)
    float* __restrict__ out_lp)      // (B,320,2000)  (d_out+1)
{
    __shared__ short Ash[20][64][8];    // 20.5 KB
    __shared__ short Bsh[20][128][8];   // 41 KB
    __shared__ float bias_p[256];
    __shared__ float bias_s[64];

    const int b   = blockIdx.z;
    const int j0  = blockIdx.y * 64;
    const int t0  = blockIdx.x * 128;
    const int tid = threadIdx.x;
    const int wv  = tid >> 6;
    const int l   = tid & 63;
    const float s = -0.00625f;

    const float* mlv_b = mlv + (size_t)b * TXT * 160;
    const float* ms_b  = ms  + (size_t)b * NMELC * MELT;

    {
        const int jj = tid >> 2;
        const int q  = tid & 3;
        const float* p = mlv_b + (size_t)(j0 + jj) * 160 + q * 20;
        float part = 0.f;
        #pragma unroll
        for (int c = 0; c < 20; ++c) {
            float mu = p[c];
            float lv = p[c + 80];
            float iv = __expf(-lv);
            part += mu * mu * iv + lv;
        }
        bias_p[tid] = part;
    }
    __syncthreads();
    if (tid < 64) {
        float v = bias_p[tid * 4] + bias_p[tid * 4 + 1] +
                  bias_p[tid * 4 + 2] + bias_p[tid * 4 + 3];
        bias_s[tid] = s * v;
    }

    // A staging: unit = (kb 0..19, j 0..63); one b128 write per unit
    #pragma unroll
    for (int r = 0; r < 5; ++r) {
        int idx = r * 256 + tid;
        int kb  = idx >> 6;
        int j   = idx & 63;
        const float* rowm = mlv_b + (size_t)(j0 + j) * 160;
        short v[8];
        if (kb < 10) {
            int c0 = kb * 8;
            #pragma unroll
            for (int e = 0; e < 8; ++e) {
                float lv = rowm[80 + c0 + e];
                v[e] = f2bf(s * __expf(-lv));
            }
        } else {
            int c0 = (kb - 10) * 8;
            #pragma unroll
            for (int e = 0; e < 8; ++e) {
                float mu = rowm[c0 + e];
                float lv = rowm[80 + c0 + e];
                v[e] = f2bf(-2.f * s * mu * __expf(-lv));
            }
        }
        *(bf16x8*)&Ash[kb][j][0] = *(bf16x8*)v;
    }

    // B staging: unit = (kbase 0..9, tg 0..1) per wave; coalesced loads,
    // two b128 writes (x^2 fragment and x fragment)
    #pragma unroll
    for (int r = 0; r < 5; ++r) {
        int unit  = r * 4 + wv;
        int kbase = unit >> 1;
        int tg    = unit & 1;
        int t     = t0 + tg * 64 + l;
        int c0    = kbase * 8;
        short vx2[8], vx[8];
        #pragma unroll
        for (int e = 0; e < 8; ++e) {
            float x = (t < MELT) ? ms_b[(size_t)(c0 + e) * MELT + t] : 0.f;
            vx2[e] = f2bf(x * x);
            vx[e]  = f2bf(x);
        }
        *(bf16x8*)&Bsh[kbase][tg * 64 + l][0]      = *(bf16x8*)vx2;
        *(bf16x8*)&Bsh[10 + kbase][tg * 64 + l][0] = *(bf16x8*)vx;
    }
    __syncthreads();

    const int lr = l & 15;
    const int lg = l >> 4;

    f32x4 acc[8];
    #pragma unroll
    for (int f = 0; f < 8; ++f) acc[f] = (f32x4){0.f, 0.f, 0.f, 0.f};

    #pragma unroll
    for (int ks = 0; ks < 5; ++ks) {
        const int kb = ks * 4 + lg;
        bf16x8 a = *(const bf16x8*)&Ash[kb][wv * 16 + lr][0];
        #pragma unroll
        for (int f = 0; f < 8; ++f) {
            bf16x8 bb = *(const bf16x8*)&Bsh[kb][f * 16 + lr][0];
            acc[f] = __builtin_amdgcn_mfma_f32_16x16x32_bf16(a, bb, acc[f],
                                                             0, 0, 0);
        }
    }

    float bs[4];
    #pragma unroll
    for (int r = 0; r < 4; ++r) bs[r] = bias_s[wv * 16 + lg * 4 + r];
    #pragma unroll
    for (int f = 0; f < 8; ++f) {
        int t = t0 + f * 16 + lr;
        if (t < MELT) {
            #pragma unroll
            for (int r = 0; r < 4; ++r) {
                int j = j0 + wv * 16 + lg * 4 + r;
                out_lp[((size_t)b * TXT + j) * MELT + t] = acc[f][r] + bs[r];
            }
        }
    }
}

// ---------------------------------------------------------------------------
// Kernel B: forward DP — VERBATIM r9/r17/r19 winner (160 us). 2 j/lane,
// systolic skew i = t + l, DPP wave_shr:1 neighbor, 3 waves + 2 LDS rings,
// 3-deep prefetch of out_lp rows, exact hardware exp2/log lse.
// ---------------------------------------------------------------------------
__global__ __launch_bounds__(192, 1) void dp_kernel(
    const float* __restrict__ lp,    // (B,320,2000) = out_lp
    const int* __restrict__ tlen,
    const int* __restrict__ mlen,
    float* __restrict__ res,
    float* __restrict__ out0)
{
    __shared__ float bnd[2][2056];
    __shared__ int   prog[2];

    const int b    = blockIdx.x;
    const int tid  = threadIdx.x;
    const int w    = tid >> 6;
    const int l    = tid & 63;
    const int tend = mlen[b] - 1;
    const int tl   = tlen[b];

    if (tid < 2) prog[tid] = 0;

    int j0c = 2 * tid; if (j0c > 318) j0c = 318;   // clamp unused lanes
    const float* r0 = lp + (size_t)(b * TXT + j0c) * MELT;
    const float* r1 = r0 + MELT;

    float A1 = (tid == 0) ? lp[(size_t)b * TXT * MELT] * L2E : -PADM;
    float A2 = -PADM;
    float A1F = A1, A2F = A2;

    if (l == 63 && w < 2) bnd[w][0] = -PADM;
    __syncthreads();

    if (w == 2 && tl < 257) return;   // wave 2 unused

    float ptA2 = -PADM, ptB2 = -PADM;
    const bool is0     = (l == 0);
    const bool isPub   = (l == 63) && (w < 2);
    const bool hasRing = (w > 0);
    int seen = 0;

    const int imax = tend + 63;

    float PA[16], PB[16], PC[16];
    #pragma unroll
    for (int q = 0; q < 8; ++q) { PA[2*q] = r0[1 + q - l]; PA[2*q+1] = r1[1 + q - l]; }
    #pragma unroll
    for (int q = 0; q < 8; ++q) { PB[2*q] = r0[9 + q - l]; PB[2*q+1] = r1[9 + q - l]; }
    #pragma unroll
    for (int q = 0; q < 16; ++q) PA[q] = fmaf(PA[q], L2E, EPSL2);

    const float* p0 = r0 + 17 - l;
    const float* p1 = r1 + 17 - l;

#define RING_RD(BQ_, T0_)                                                    \
    {                                                                        \
        float4 q0_ = *(const float4*)&bnd[w - 1][T0_];                       \
        float4 q1_ = *(const float4*)&bnd[w - 1][(T0_) + 4];                 \
        BQ_[0]=q0_.x; BQ_[1]=q0_.y; BQ_[2]=q0_.z; BQ_[3]=q0_.w;              \
        BQ_[4]=q1_.x; BQ_[5]=q1_.y; BQ_[6]=q1_.z; BQ_[7]=q1_.w;              \
    }
#define RING_POLL(NEED_)                                                     \
    if (seen < (NEED_)) {                                                    \
        int tgt_ = (NEED_) + 32;                                             \
        if (tgt_ > tend - 1) tgt_ = tend - 1;                                \
        if (tgt_ < (NEED_)) tgt_ = (NEED_);                                  \
        volatile int* pv_ = &prog[w - 1];                                    \
        int v_ = *pv_;                                                       \
        while (v_ < tgt_) { __builtin_amdgcn_s_sleep(1); v_ = *pv_; }        \
        seen = v_;                                                           \
        __asm__ volatile("" ::: "memory");                                   \
    }

    float bqC[8];
    if (hasRing) {
        RING_POLL(7)
        RING_RD(bqC, 0)
    } else {
        #pragma unroll
        for (int q = 0; q < 8; ++q) bqC[q] = -PADM;
    }

#define STEP2(Pc_, q_, AQ_)                                                  \
    {                                                                        \
        float pt_ = is0 ? bqC[q_] : ptA2;                                    \
        float m1_ = fmaxf(A1, pt_);                                          \
        float d1_ = A1 - pt_;                                                \
        float e1_ = __builtin_amdgcn_exp2f(-fabsf(d1_));                     \
        float g1_ = __builtin_amdgcn_logf(1.0f + e1_);                       \
        float n1_ = m1_ + g1_ + Pc_[2 * q_];                                 \
        float m2_ = fmaxf(A2, A1);                                           \
        float d2_ = A2 - A1;                                                 \
        float e2_ = __builtin_amdgcn_exp2f(-fabsf(d2_));                     \
        float g2_ = __builtin_amdgcn_logf(1.0f + e2_);                       \
        float n2_ = m2_ + g2_ + Pc_[2 * q_ + 1];                             \
        float ns_ = dpp_shr1(n2_);                                           \
        ptA2 = ptB2; ptB2 = ns_;                                             \
        A1 = n1_; A2 = n2_; AQ_ = n2_;                                       \
    }

#define GROUP2_S(Pc_, Pm_, Pl_, I0_)                                         \
{                                                                            \
    float bqN[8];                                                            \
    if (hasRing) {                                                           \
        const int nt0_ = (I0_) + 7;                                          \
        RING_POLL(nt0_ + 7)                                                  \
        RING_RD(bqN, nt0_)                                                   \
    } else {                                                                 \
        _Pragma("unroll") for (int q_=0;q_<8;++q_) bqN[q_] = -PADM;          \
    }                                                                        \
    _Pragma("unroll") for (int q_=0;q_<8;++q_) {                             \
        Pl_[2*q_] = p0[q_]; Pl_[2*q_+1] = p1[q_];                            \
    }                                                                        \
    float aq2[8];                                                            \
    _Pragma("unroll")                                                        \
    for (int q_=0;q_<8;++q_) STEP2(Pc_, q_, aq2[q_])                         \
    if (isPub) {                                                             \
        const int t63_ = (I0_) - 63;                                         \
        if (t63_ >= 1) {                                                     \
            _Pragma("unroll") for (int q_=0;q_<8;++q_)                       \
                bnd[w][t63_ + q_] = aq2[q_];                                 \
        } else {                                                             \
            _Pragma("unroll") for (int q_=0;q_<8;++q_)                       \
                if (t63_ + q_ >= 1) bnd[w][t63_ + q_] = aq2[q_];             \
        }                                                                    \
        __asm__ volatile("" ::: "memory");  /* DS pipe is in-order */        \
        int pgv_ = t63_ + 7;                                                 \
        if (pgv_ >= 1) prog[w] = pgv_;                                       \
    }                                                                        \
    p0 += 8; p1 += 8;                                                        \
    _Pragma("unroll") for (int q_=0;q_<16;++q_)                              \
        Pm_[q_] = fmaf(Pm_[q_], L2E, EPSL2);                                 \
    _Pragma("unroll") for (int q_=0;q_<8;++q_) bqC[q_] = bqN[q_];            \
}

#define GROUP2_T(Pc_, Pm_, Pl_, I0_)                                         \
{                                                                            \
    float bqN[8];                                                            \
    if (hasRing) {                                                           \
        const int nt0_ = (I0_) + 7;                                          \
        int need_ = nt0_ + 7; if (need_ > tend - 1) need_ = tend - 1;        \
        RING_POLL(need_)                                                     \
        const int rb_ = nt0_ > 2048 ? 2048 : nt0_;                           \
        RING_RD(bqN, rb_)                                                    \
    } else {                                                                 \
        _Pragma("unroll") for (int q_=0;q_<8;++q_) bqN[q_] = -PADM;          \
    }                                                                        \
    _Pragma("unroll") for (int q_=0;q_<8;++q_) {                             \
        int t_ = (I0_) + 16 + q_ - l;                                        \
        t_ = t_ < 0 ? 0 : (t_ > tend ? tend : t_);                           \
        Pl_[2*q_] = r0[t_]; Pl_[2*q_+1] = r1[t_];                            \
    }                                                                        \
    float aq2[8];                                                            \
    const int vt_ = (I0_) - l;                                               \
    _Pragma("unroll")                                                        \
    for (int q_=0;q_<8;++q_) {                                               \
        STEP2(Pc_, q_, aq2[q_])                                              \
        bool c_ = (vt_ + q_ == tend);                                        \
        A1F = c_ ? A1 : A1F;                                                 \
        A2F = c_ ? A2 : A2F;                                                 \
    }                                                                        \
    if (isPub) {                                                             \
        const int t63_ = (I0_) - 63;                                         \
        _Pragma("unroll") for (int q_=0;q_<8;++q_) {                         \
            int tq_ = t63_ + q_;                                             \
            if (tq_ >= 1 && tq_ <= tend) bnd[w][tq_] = aq2[q_];              \
        }                                                                    \
        __asm__ volatile("" ::: "memory");                                   \
        int pgv_ = t63_ + 7; if (pgv_ > tend) pgv_ = tend;                   \
        if (pgv_ >= 1) prog[w] = pgv_;                                       \
    }                                                                        \
    _Pragma("unroll") for (int q_=0;q_<16;++q_)                              \
        Pm_[q_] = fmaf(Pm_[q_], L2E, EPSL2);                                 \
    _Pragma("unroll") for (int q_=0;q_<8;++q_) bqC[q_] = bqN[q_];            \
}

    int i0 = 1;
    const int sEnd = tend - 23;   // steady: loads in-bounds, latch can't fire
    int ph = 0;
    while (i0 <= sEnd) {
        GROUP2_S(PA, PB, PC, i0); i0 += 8;
        if (i0 > sEnd) { ph = 1; break; }
        GROUP2_S(PB, PC, PA, i0); i0 += 8;
        if (i0 > sEnd) { ph = 2; break; }
        GROUP2_S(PC, PA, PB, i0); i0 += 8;
    }
    if (ph == 1) {
        #pragma unroll
        for (int q = 0; q < 16; ++q) {
            float tmp = PA[q]; PA[q] = PB[q]; PB[q] = PC[q]; PC[q] = tmp;
        }
    } else if (ph == 2) {
        #pragma unroll
        for (int q = 0; q < 16; ++q) {
            float tmp = PA[q]; PA[q] = PC[q]; PC[q] = PB[q]; PB[q] = tmp;
        }
    }
    while (i0 <= imax) {
        GROUP2_T(PA, PB, PC, i0); i0 += 8;
        if (i0 > imax) break;
        GROUP2_T(PB, PC, PA, i0); i0 += 8;
        if (i0 > imax) break;
        GROUP2_T(PC, PA, PB, i0); i0 += 8;
    }

#undef GROUP2_S
#undef GROUP2_T
#undef STEP2
#undef RING_RD
#undef RING_POLL

    if (tid == ((tl - 1) >> 1)) {
        float Af = ((tl - 1) & 1) ? A2F : A1F;
        float v = Af * LN2 / (float)(tend + 1);
        if (res) res[b] = v;
        else     atomicAdd(out0, -v / (float)BATCH);
    }
}

__global__ void zero1_kernel(float* out0) { out0[0] = 0.f; }

__global__ void fin_kernel(const float* __restrict__ res, float* __restrict__ out0)
{
    int l = threadIdx.x;
    float v = (l < BATCH) ? res[l] : 0.f;
    #pragma unroll
    for (int off = 32; off; off >>= 1) v += __shfl_down(v, off);
    if (l == 0) out0[0] = -(v / (float)BATCH);
}

// ---------------------------------------------------------------------------
extern "C" void kernel_launch(void* const* d_in, const int* in_sizes, int n_in,
                              void* d_out, int out_size, void* d_ws, size_t ws_size,
                              hipStream_t stream)
{
    const float* mlv = (const float*)d_in[0];
    const float* ms  = (const float*)d_in[1];
    const int*   tl  = (const int*)d_in[2];
    const int*   ml  = (const int*)d_in[3];
    float* out    = (float*)d_out;
    float* out_lp = out + 1;

    bool res_ok = ws_size >= 64;
    float* res = res_ok ? (float*)d_ws : nullptr;

    dim3 gA(16, 5, 16);   // t-tiles(128), j-tiles(64), batch
    lp_kernel<<<gA, 256, 0, stream>>>(mlv, ms, out_lp);

    if (!res_ok) zero1_kernel<<<1, 1, 0, stream>>>(out);
    dp_kernel<<<BATCH, 192, 0, stream>>>(out_lp, tl, ml, res, out);
    if (res_ok) fin_kernel<<<1, 64, 0, stream>>>(res, out);
}